// Round 19
// baseline (21.369 us; speedup 1.0000x reference)
//
#include <hip/hip_runtime.h>

// MPO/TT embedding: out[t] = A2[h(t)] (16x64) . B3[l(t)] (64x48)
// cores: c0 (1,8,4,32) c1 (32,8,4,64) c2 (64,8,4,64) c3 (64,8,4,24) c4 (24,8,3,1)
// v = token id; h = v>>9 (i1=h>>3,i2=h&7); l = v&511 (i3=l>>6, l2=l&63, i4=l2>>3, i5=l2&7)
// o = o12*48 + o345 ; o12 (16,=M) ; o345 = o3*12+o4*3+o5 (48) ; r2 = K (64)
//
// R19: R18 minus the aFrag LDS staging. Phase 2 loads its A-fragments DIRECTLY
// from c2 (L2-resident 64KB i3-slice, shared by 64 blocks) in fragment order:
// lane (lh,mm), frag (mtl,ks) <- two float4 at c2[r2(m)][i3][o3(m)][ks*32+lh*8].
// Removes 32KB LDS (3->8 blocks/CU capacity), one sync, all A LDS traffic.
// Values bit-identical to R18 (same f2bf of same f32 inputs).
//
// Fragment layouts (R13/R14/R17-validated on HW):
//   A-frag: lane = lh*16+m holds k = ks*32+lh*8+j, j=0..7
//   B-frag: lane = lh*16+n, same k packing
//   A2Tb[h][ks][lane][j] : 128 KB
//   C/D: col(n) = lane&15, row(m) = (lane>>4)*4+reg

typedef __attribute__((ext_vector_type(8))) short bf16x8;
typedef __attribute__((ext_vector_type(4))) float f32x4;

__device__ __forceinline__ unsigned short f2bf(float x) {
    unsigned u = __float_as_uint(x);
    unsigned r = (u + 0x7FFFu + ((u >> 16) & 1u)) >> 16;   // RNE
    return (unsigned short)r;
}

__device__ __forceinline__ bf16x8 pack8(float4 v0, float4 v1) {
    union { unsigned u[4]; bf16x8 v; } r;
    r.u[0] = (unsigned)f2bf(v0.x) | ((unsigned)f2bf(v0.y) << 16);
    r.u[1] = (unsigned)f2bf(v0.z) | ((unsigned)f2bf(v0.w) << 16);
    r.u[2] = (unsigned)f2bf(v1.x) | ((unsigned)f2bf(v1.y) << 16);
    r.u[3] = (unsigned)f2bf(v1.z) | ((unsigned)f2bf(v1.w) << 16);
    return r.v;
}

// ---- prep: A2 fragments only (64 blocks, R14/R17 verbatim) ----
__global__ __launch_bounds__(256) void k_prepA(const float* __restrict__ c0,
                                               const float* __restrict__ c1,
                                               unsigned short* __restrict__ A2Tb) {
    const int t = threadIdx.x;
    if (t >= 128) return;
    int h = blockIdx.x;
    int i1 = h >> 3, i2 = h & 7;
    int m = t & 15, kc = t >> 4;            // kc 0..7 ; r2 = kc*8 + j
    int o1 = m >> 2, o2 = m & 3;
    const float* c0r = c0 + i1 * 128 + o1 * 32;
    const float* c1p = c1 + i2 * 256 + o2 * 64 + kc * 8;
    float s[8] = {};
#pragma unroll
    for (int r1 = 0; r1 < 32; ++r1) {
        float a = c0r[r1];
        float4 v0 = *reinterpret_cast<const float4*>(c1p + r1 * 2048);
        float4 v1 = *reinterpret_cast<const float4*>(c1p + r1 * 2048 + 4);
        s[0] += a * v0.x; s[1] += a * v0.y; s[2] += a * v0.z; s[3] += a * v0.w;
        s[4] += a * v1.x; s[5] += a * v1.y; s[6] += a * v1.z; s[7] += a * v1.w;
    }
    int ks = kc >> 2, lh = kc & 3;          // lane = lh*16 + m
    unsigned short* dst = A2Tb + (size_t)(((h * 2 + ks) * 64 + lh * 16 + m)) * 8;
    *reinterpret_cast<ushort4*>(dst) =
        make_ushort4(f2bf(s[0]), f2bf(s[1]), f2bf(s[2]), f2bf(s[3]));
    *reinterpret_cast<ushort4*>(dst + 4) =
        make_ushort4(f2bf(s[4]), f2bf(s[5]), f2bf(s[6]), f2bf(s[7]));
}

// ---- main: block per l; B3 in-LDS via MFMA with direct-from-c2 A-frags ----
#define MAX_TOK 128
__global__ __launch_bounds__(256) void k_mainL(const int* __restrict__ ids,
                                               const float* __restrict__ c2,
                                               const float* __restrict__ c3,
                                               const float* __restrict__ c4,
                                               const unsigned short* __restrict__ A2Tb,
                                               float* __restrict__ out,
                                               int n_tokens) {
    const int l = blockIdx.x;
    const int t = threadIdx.x;
    const int i3 = l >> 6, l2 = l & 63;
    const int i4 = l2 >> 3, i5 = l2 & 7;
    const int w = t >> 6, lane = t & 63;

    __shared__ unsigned short bFrag[2 * 64 * 8];       // 2 KB  [ks][lane][j]
    __shared__ unsigned short bFrag2[3 * 2 * 64 * 8];  // 6 KB  [nt][ks][lane][j]
    __shared__ int s_list[MAX_TOK];
    __shared__ int s_cnt;

    // phase 0: init (bFrag fully zeroed: N=12<16 padding must be 0)
    if (t == 0) s_cnt = 0;
    reinterpret_cast<int*>(bFrag)[t] = 0;
    reinterpret_cast<int*>(bFrag)[t + 256] = 0;
    __syncthreads();

    // phase 1a: scan & bucket tokens with l(v)==l
    for (int i = t; i < n_tokens; i += 256) {
        int v = ids[i];
        if ((v & 511) == l) {
            int p = atomicAdd(&s_cnt, 1);
            if (p < MAX_TOK) s_list[p] = (i << 6) | (v >> 9);
        }
    }

    // phase 1b: B4[l2][r3][o45] -> bf16 B-frags (thread: r3 = t>>2, o4 = t&3)
    {
        int r3 = t >> 2, o4 = t & 3;
        const float* c3p = c3 + r3 * 768 + i4 * 96 + o4 * 24;
        float cc[24];
#pragma unroll
        for (int q = 0; q < 6; ++q) {
            float4 v = *reinterpret_cast<const float4*>(c3p + q * 4);
            cc[q * 4 + 0] = v.x; cc[q * 4 + 1] = v.y;
            cc[q * 4 + 2] = v.z; cc[q * 4 + 3] = v.w;
        }
        float s0 = 0.f, s1 = 0.f, s2 = 0.f;
        const float* c4b = c4 + i5 * 3;
#pragma unroll
        for (int r4 = 0; r4 < 24; ++r4) {
            float a = cc[r4];
            const float* bb = c4b + r4 * 24;
            s0 += a * bb[0];
            s1 += a * bb[1];
            s2 += a * bb[2];
        }
        int ks = r3 >> 5, lh = (r3 >> 3) & 3, j = r3 & 7;
        int n0 = o4 * 3;
        bFrag[(ks * 64 + lh * 16 + n0 + 0) * 8 + j] = f2bf(s0);
        bFrag[(ks * 64 + lh * 16 + n0 + 1) * 8 + j] = f2bf(s1);
        bFrag[(ks * 64 + lh * 16 + n0 + 2) * 8 + j] = f2bf(s2);
    }
    __syncthreads();

    const int cnt = (s_cnt < MAX_TOK) ? s_cnt : MAX_TOK;
    if (cnt == 0) return;

    // phase 2: B3 = C2slice . B4 (M=256,N=12,K=64); A-frags direct from c2
    {
        const bf16x8* Bf = reinterpret_cast<const bf16x8*>(bFrag);
        bf16x8 b0 = Bf[lane];
        bf16x8 b1 = Bf[64 + lane];
        f32x4 z = {0.f, 0.f, 0.f, 0.f};
        const int mm = lane & 15, lh = lane >> 4;
        const int row4 = (lane >> 4) * 4, ncol = lane & 15;
        const float* cbase = c2 + i3 * 256 + lh * 8;
#pragma unroll
        for (int mi = 0; mi < 4; ++mi) {
            int mtl = w * 4 + mi;
            int m = mtl * 16 + mm;
            int r2 = m >> 2, o3 = m & 3;
            const float* base = cbase + r2 * 2048 + o3 * 64;
            float4 v0 = *reinterpret_cast<const float4*>(base);
            float4 v1 = *reinterpret_cast<const float4*>(base + 4);
            float4 v2 = *reinterpret_cast<const float4*>(base + 32);
            float4 v3 = *reinterpret_cast<const float4*>(base + 36);
            bf16x8 a0 = pack8(v0, v1);
            bf16x8 a1 = pack8(v2, v3);
            f32x4 acc = __builtin_amdgcn_mfma_f32_16x16x32_bf16(a0, b0, z, 0, 0, 0);
            acc       = __builtin_amdgcn_mfma_f32_16x16x32_bf16(a1, b1, acc, 0, 0, 0);
            if (ncol < 12) {
#pragma unroll
                for (int reg = 0; reg < 4; ++reg) {
                    int mr = mtl * 16 + row4 + reg;
                    int r2r = mr >> 2, o3r = mr & 3;
                    int o345 = o3r * 12 + ncol;
                    int nt2 = o345 >> 4, n2 = o345 & 15;
                    int ks2 = r2r >> 5, lh2 = (r2r >> 3) & 3, j2 = r2r & 7;
                    bFrag2[((nt2 * 2 + ks2) * 64 + lh2 * 16 + n2) * 8 + j2] =
                        f2bf(acc[reg]);
                }
            }
        }
    }
    __syncthreads();

    // phase 3: per-token product (wave-parallel, no syncs)
    {
        const bf16x8* B = reinterpret_cast<const bf16x8*>(bFrag2);
        f32x4 z = {0.f, 0.f, 0.f, 0.f};
        for (int k = w; k < cnt; k += 4) {
            int e = s_list[k];
            int token = e >> 6, h = e & 63;
            const bf16x8* A = reinterpret_cast<const bf16x8*>(A2Tb) + h * 128 + lane;
            bf16x8 a0 = A[0];
            bf16x8 a1 = A[64];

            f32x4 acc0 = __builtin_amdgcn_mfma_f32_16x16x32_bf16(a0, B[lane],       z, 0, 0, 0);
            acc0       = __builtin_amdgcn_mfma_f32_16x16x32_bf16(a1, B[64 + lane],  acc0, 0, 0, 0);
            f32x4 acc1 = __builtin_amdgcn_mfma_f32_16x16x32_bf16(a0, B[128 + lane], z, 0, 0, 0);
            acc1       = __builtin_amdgcn_mfma_f32_16x16x32_bf16(a1, B[192 + lane], acc1, 0, 0, 0);
            f32x4 acc2 = __builtin_amdgcn_mfma_f32_16x16x32_bf16(a0, B[256 + lane], z, 0, 0, 0);
            acc2       = __builtin_amdgcn_mfma_f32_16x16x32_bf16(a1, B[320 + lane], acc2, 0, 0, 0);

            const int n = lane & 15;
            float* o = out + (size_t)token * 768 + ((lane >> 4) * 4) * 48 + n;
#pragma unroll
            for (int reg = 0; reg < 4; ++reg) {
                o[reg * 48 + 0]  = acc0[reg];
                o[reg * 48 + 16] = acc1[reg];
                o[reg * 48 + 32] = acc2[reg];
            }
        }
    }
}

extern "C" void kernel_launch(void* const* d_in, const int* in_sizes, int n_in,
                              void* d_out, int out_size, void* d_ws, size_t ws_size,
                              hipStream_t stream) {
    const int*   ids = (const int*)d_in[0];
    const float* c0  = (const float*)d_in[1];
    const float* c1  = (const float*)d_in[2];
    const float* c2  = (const float*)d_in[3];
    const float* c3  = (const float*)d_in[4];
    const float* c4  = (const float*)d_in[5];
    float* out = (float*)d_out;

    char* ws = (char*)d_ws;
    unsigned short* A2Tb = (unsigned short*)(ws + 0);   // 131072 B

    int n_tokens = in_sizes[0];             // 8*512 = 4096

    k_prepA<<<64, 256, 0, stream>>>(c0, c1, A2Tb);
    k_mainL<<<512, 256, 0, stream>>>(ids, c2, c3, c4, A2Tb, out, n_tokens);
}

// Round 20
// 18.454 us; speedup vs baseline: 1.1579x; 1.1579x over previous
//
#include <hip/hip_runtime.h>

// MPO/TT embedding: out[t] = A2[h(t)] (16x64) . B3[l(t)] (64x48)
// cores: c0 (1,8,4,32) c1 (32,8,4,64) c2 (64,8,4,64) c3 (64,8,4,24) c4 (24,8,3,1)
// v = token id; h = v>>9 (i1=h>>3,i2=h&7); l = v&511 (i3=l>>6, l2=l&63, i4=l2>>3, i5=l2&7)
// o = o12*48 + o345 ; o12 (16,=M) ; o345 = o3*12+o4*3+o5 (48) ; r2 = K (64)
//
// R20: R18 dataflow (validated, 20.0us) with 512-thread blocks (8 waves) for
// 2x latency hiding: all threads scan (8 iters); waves 0-3 stage c2->aFrag
// while waves 4-7 compute B4->bFrag (independent LDS, single sync); phase-2
// GEMM = 2 mtl/wave; phase-3 = ~1 token/wave. Values bit-identical to R18.
//
// Fragment layouts (R13/R14/R17-validated on HW):
//   A-frag: lane = lh*16+m holds k = ks*32+lh*8+j, j=0..7
//   B-frag: lane = lh*16+n, same k packing
//   A2Tb[h][ks][lane][j] : 128 KB
//   C/D: col(n) = lane&15, row(m) = (lane>>4)*4+reg

typedef __attribute__((ext_vector_type(8))) short bf16x8;
typedef __attribute__((ext_vector_type(4))) float f32x4;

__device__ __forceinline__ unsigned short f2bf(float x) {
    unsigned u = __float_as_uint(x);
    unsigned r = (u + 0x7FFFu + ((u >> 16) & 1u)) >> 16;   // RNE
    return (unsigned short)r;
}

// ---- prep: A2 fragments only (64 blocks, R14/R17 verbatim) ----
__global__ __launch_bounds__(256) void k_prepA(const float* __restrict__ c0,
                                               const float* __restrict__ c1,
                                               unsigned short* __restrict__ A2Tb) {
    const int t = threadIdx.x;
    if (t >= 128) return;
    int h = blockIdx.x;
    int i1 = h >> 3, i2 = h & 7;
    int m = t & 15, kc = t >> 4;            // kc 0..7 ; r2 = kc*8 + j
    int o1 = m >> 2, o2 = m & 3;
    const float* c0r = c0 + i1 * 128 + o1 * 32;
    const float* c1p = c1 + i2 * 256 + o2 * 64 + kc * 8;
    float s[8] = {};
#pragma unroll
    for (int r1 = 0; r1 < 32; ++r1) {
        float a = c0r[r1];
        float4 v0 = *reinterpret_cast<const float4*>(c1p + r1 * 2048);
        float4 v1 = *reinterpret_cast<const float4*>(c1p + r1 * 2048 + 4);
        s[0] += a * v0.x; s[1] += a * v0.y; s[2] += a * v0.z; s[3] += a * v0.w;
        s[4] += a * v1.x; s[5] += a * v1.y; s[6] += a * v1.z; s[7] += a * v1.w;
    }
    int ks = kc >> 2, lh = kc & 3;          // lane = lh*16 + m
    unsigned short* dst = A2Tb + (size_t)(((h * 2 + ks) * 64 + lh * 16 + m)) * 8;
    *reinterpret_cast<ushort4*>(dst) =
        make_ushort4(f2bf(s[0]), f2bf(s[1]), f2bf(s[2]), f2bf(s[3]));
    *reinterpret_cast<ushort4*>(dst + 4) =
        make_ushort4(f2bf(s[4]), f2bf(s[5]), f2bf(s[6]), f2bf(s[7]));
}

// ---- main: block per l, 8 waves; B3 in-LDS via MFMA; tokens wave-parallel ----
#define MAX_TOK 128
__global__ __launch_bounds__(512) void k_mainL(const int* __restrict__ ids,
                                               const float* __restrict__ c2,
                                               const float* __restrict__ c3,
                                               const float* __restrict__ c4,
                                               const unsigned short* __restrict__ A2Tb,
                                               float* __restrict__ out,
                                               int n_tokens) {
    const int l = blockIdx.x;
    const int t = threadIdx.x;
    const int i3 = l >> 6, l2 = l & 63;
    const int i4 = l2 >> 3, i5 = l2 & 7;
    const int w = t >> 6, lane = t & 63;

    __shared__ unsigned short aFrag[16 * 2 * 64 * 8];  // 32 KB [mtl][ks][lane][j]
    __shared__ unsigned short bFrag[2 * 64 * 8];       // 2 KB  [ks][lane][j]
    __shared__ unsigned short bFrag2[3 * 2 * 64 * 8];  // 6 KB  [nt][ks][lane][j]
    __shared__ int s_list[MAX_TOK];
    __shared__ int s_cnt;

    // phase 0: init (bFrag fully zeroed: N=12<16 padding must be 0)
    if (t == 0) s_cnt = 0;
    reinterpret_cast<int*>(bFrag)[t] = 0;      // 512 ints = whole bFrag
    __syncthreads();

    // phase 1a: all 512 threads scan & bucket (8 iters)
    for (int i = t; i < n_tokens; i += 512) {
        int v = ids[i];
        if ((v & 511) == l) {
            int p = atomicAdd(&s_cnt, 1);
            if (p < MAX_TOK) s_list[p] = (i << 6) | (v >> 9);
        }
    }

    if (t < 256) {
        // phase 1b (waves 0-3): stage c2 i3-slice -> bf16 A-frags (R18 verbatim)
        int o3 = lane >> 4, chunk = lane & 15;
        int ks = chunk >> 3, lh = (chunk >> 1) & 3, e4 = (chunk & 1) * 4;
#pragma unroll
        for (int it = 0; it < 16; ++it) {
            int r2 = w + 4 * it;
            float4 v = *reinterpret_cast<const float4*>(
                c2 + r2 * 2048 + i3 * 256 + o3 * 64 + chunk * 4);
            int m = r2 * 4 + o3;
            int mtl = m >> 4, mm = m & 15;
            unsigned short* dst = aFrag +
                (((mtl * 2 + ks) * 64 + lh * 16 + mm) * 8 + e4);
            *reinterpret_cast<ushort4*>(dst) =
                make_ushort4(f2bf(v.x), f2bf(v.y), f2bf(v.z), f2bf(v.w));
        }
    } else {
        // phase 1c (waves 4-7): B4[l2][r3][o45] -> bf16 B-frags (R18 verbatim)
        int t2 = t - 256;
        int r3 = t2 >> 2, o4 = t2 & 3;
        const float* c3p = c3 + r3 * 768 + i4 * 96 + o4 * 24;
        float cc[24];
#pragma unroll
        for (int q = 0; q < 6; ++q) {
            float4 v = *reinterpret_cast<const float4*>(c3p + q * 4);
            cc[q * 4 + 0] = v.x; cc[q * 4 + 1] = v.y;
            cc[q * 4 + 2] = v.z; cc[q * 4 + 3] = v.w;
        }
        float s0 = 0.f, s1 = 0.f, s2 = 0.f;
        const float* c4b = c4 + i5 * 3;
#pragma unroll
        for (int r4 = 0; r4 < 24; ++r4) {
            float a = cc[r4];
            const float* bb = c4b + r4 * 24;
            s0 += a * bb[0];
            s1 += a * bb[1];
            s2 += a * bb[2];
        }
        int ks = r3 >> 5, lh = (r3 >> 3) & 3, j = r3 & 7;
        int n0 = o4 * 3;
        bFrag[(ks * 64 + lh * 16 + n0 + 0) * 8 + j] = f2bf(s0);
        bFrag[(ks * 64 + lh * 16 + n0 + 1) * 8 + j] = f2bf(s1);
        bFrag[(ks * 64 + lh * 16 + n0 + 2) * 8 + j] = f2bf(s2);
    }
    __syncthreads();

    const int cnt = (s_cnt < MAX_TOK) ? s_cnt : MAX_TOK;
    if (cnt == 0) return;

    // phase 2: B3 = C2slice . B4 (M=256,N=12,K=64); 2 mtl per wave
    {
        const bf16x8* A = reinterpret_cast<const bf16x8*>(aFrag);
        const bf16x8* Bf = reinterpret_cast<const bf16x8*>(bFrag);
        bf16x8 b0 = Bf[lane];
        bf16x8 b1 = Bf[64 + lane];
        f32x4 z = {0.f, 0.f, 0.f, 0.f};
        int row4 = (lane >> 4) * 4, ncol = lane & 15;
#pragma unroll
        for (int mi = 0; mi < 2; ++mi) {
            int mtl = w * 2 + mi;
            bf16x8 a0 = A[(mtl * 2 + 0) * 64 + lane];
            bf16x8 a1 = A[(mtl * 2 + 1) * 64 + lane];
            f32x4 acc = __builtin_amdgcn_mfma_f32_16x16x32_bf16(a0, b0, z, 0, 0, 0);
            acc       = __builtin_amdgcn_mfma_f32_16x16x32_bf16(a1, b1, acc, 0, 0, 0);
            if (ncol < 12) {
#pragma unroll
                for (int reg = 0; reg < 4; ++reg) {
                    int m = mtl * 16 + row4 + reg;
                    int r2 = m >> 2, o3 = m & 3;
                    int o345 = o3 * 12 + ncol;
                    int nt2 = o345 >> 4, n2 = o345 & 15;
                    int ks2 = r2 >> 5, lh2 = (r2 >> 3) & 3, j2 = r2 & 7;
                    bFrag2[((nt2 * 2 + ks2) * 64 + lh2 * 16 + n2) * 8 + j2] =
                        f2bf(acc[reg]);
                }
            }
        }
    }
    __syncthreads();

    // phase 3: per-token product (wave-parallel, ~1 token/wave)
    {
        const bf16x8* B = reinterpret_cast<const bf16x8*>(bFrag2);
        f32x4 z = {0.f, 0.f, 0.f, 0.f};
        for (int k = w; k < cnt; k += 8) {
            int e = s_list[k];
            int token = e >> 6, h = e & 63;
            const bf16x8* A = reinterpret_cast<const bf16x8*>(A2Tb) + h * 128 + lane;
            bf16x8 a0 = A[0];
            bf16x8 a1 = A[64];

            f32x4 acc0 = __builtin_amdgcn_mfma_f32_16x16x32_bf16(a0, B[lane],       z, 0, 0, 0);
            acc0       = __builtin_amdgcn_mfma_f32_16x16x32_bf16(a1, B[64 + lane],  acc0, 0, 0, 0);
            f32x4 acc1 = __builtin_amdgcn_mfma_f32_16x16x32_bf16(a0, B[128 + lane], z, 0, 0, 0);
            acc1       = __builtin_amdgcn_mfma_f32_16x16x32_bf16(a1, B[192 + lane], acc1, 0, 0, 0);
            f32x4 acc2 = __builtin_amdgcn_mfma_f32_16x16x32_bf16(a0, B[256 + lane], z, 0, 0, 0);
            acc2       = __builtin_amdgcn_mfma_f32_16x16x32_bf16(a1, B[320 + lane], acc2, 0, 0, 0);

            const int n = lane & 15;
            float* o = out + (size_t)token * 768 + ((lane >> 4) * 4) * 48 + n;
#pragma unroll
            for (int reg = 0; reg < 4; ++reg) {
                o[reg * 48 + 0]  = acc0[reg];
                o[reg * 48 + 16] = acc1[reg];
                o[reg * 48 + 32] = acc2[reg];
            }
        }
    }
}

extern "C" void kernel_launch(void* const* d_in, const int* in_sizes, int n_in,
                              void* d_out, int out_size, void* d_ws, size_t ws_size,
                              hipStream_t stream) {
    const int*   ids = (const int*)d_in[0];
    const float* c0  = (const float*)d_in[1];
    const float* c1  = (const float*)d_in[2];
    const float* c2  = (const float*)d_in[3];
    const float* c3  = (const float*)d_in[4];
    const float* c4  = (const float*)d_in[5];
    float* out = (float*)d_out;

    char* ws = (char*)d_ws;
    unsigned short* A2Tb = (unsigned short*)(ws + 0);   // 131072 B

    int n_tokens = in_sizes[0];             // 8*512 = 4096

    k_prepA<<<64, 256, 0, stream>>>(c0, c1, A2Tb);
    k_mainL<<<512, 512, 0, stream>>>(ids, c2, c3, c4, A2Tb, out, n_tokens);
}